// Round 13
// baseline (109.256 us; speedup 1.0000x reference)
//
#include <hip/hip_runtime.h>

#define IDX_BASE 16777216UL   // 4096*64*64
#define LOSS_IDX 17039360UL   // IDX_BASE + 4096*64
#define EPS2 0.02f            // rescue window on (M1 - M2); score err bound ~1e-3

typedef float4 f4;
typedef _Float16 half8 __attribute__((ext_vector_type(8)));
typedef float f32x4 __attribute__((ext_vector_type(4)));

// ---- precompute code A-fragments (f16 hi/lo) + fused c2 table (R12-validated).
//      unit u = tile*4 + s*2 + hl; fragbuf[m][u][lane] : half8 ----
__global__ __launch_bounds__(256) void pq_frag(const float* __restrict__ cb,
                                               half8* __restrict__ fragbuf,
                                               float* __restrict__ c2) {
    int m = blockIdx.x, tid = threadIdx.x;
    int w = tid >> 6, lane = tid & 63, lh = lane >> 4, l15 = lane & 15;
    const float* cbm = cb + (size_t)m * (256 * 64);
    half8* fbm = fragbuf + (size_t)m * (16 * 4 * 64);
    #pragma unroll
    for (int ti = 0; ti < 4; ++ti) {
        int tile = w * 4 + ti;
        int code = tile * 16 + l15;
        const float* crow = cbm + code * 64 + lh * 8;
        float ss = 0.f;
        #pragma unroll
        for (int s = 0; s < 2; ++s) {
            f4 a = *reinterpret_cast<const f4*>(crow + s * 32);
            f4 b = *reinterpret_cast<const f4*>(crow + s * 32 + 4);
            float v[8] = {a.x, a.y, a.z, a.w, b.x, b.y, b.z, b.w};
            half8 hi, lo;
            #pragma unroll
            for (int e = 0; e < 8; ++e) {
                _Float16 h = (_Float16)v[e];
                hi[e] = h; lo[e] = (_Float16)(v[e] - (float)h);
                ss = fmaf(v[e], v[e], ss);
            }
            fbm[(tile * 4 + s * 2 + 0) * 64 + lane] = hi;
            fbm[(tile * 4 + s * 2 + 1) * 64 + lane] = lo;
        }
        ss += __shfl_xor(ss, 16, 64);
        ss += __shfl_xor(ss, 32, 64);
        if (lh == 0) c2[m * 256 + code] = ss;
    }
}

// ---- score: MFMA argmin ONLY. No LDS, no barriers, no epilogue state.
//      Wave = 32 rows x 256 codes; writes idxws[m][b] (int, 64B-contiguous). ----
__global__ __launch_bounds__(256, 4) void pq_score(
    const float* __restrict__ z, const float* __restrict__ cb,
    const float* __restrict__ c2ws, const half8* __restrict__ fragbuf,
    int* __restrict__ idxws)
{
    const int tid = threadIdx.x, bx = blockIdx.x;
    const int m = ((bx & 7) << 3) | ((bx >> 3) & 7);   // XCD-aware m-octet (R11-proven)
    const int chunk = bx >> 6;                          // 0..31
    const int w = tid >> 6, lane = tid & 63;
    const int lh = lane >> 4, l15 = lane & 15;
    const int rowbase = chunk * 128 + w * 32;

    const float* __restrict__ cbm = cb + (size_t)m * (256 * 64);
    const f4* cb4m = reinterpret_cast<const f4*>(cbm);
    const half8* __restrict__ fb = fragbuf + (size_t)m * (16 * 4 * 64);
    const f4* __restrict__ c2t = reinterpret_cast<const f4*>(c2ws + m * 256);

    // resident z B-fragments (R10-validated conversion)
    half8 zh0[2], zl0[2], zh1[2], zl1[2];
    #pragma unroll
    for (int h = 0; h < 2; ++h) {
        size_t rh = (size_t)(rowbase + h * 16 + l15);
        const float* zb = z + (rh * 64 + m) * 64 + lh * 8;
        f4 p0 = *reinterpret_cast<const f4*>(zb);
        f4 p1 = *reinterpret_cast<const f4*>(zb + 4);
        f4 p2 = *reinterpret_cast<const f4*>(zb + 32);
        f4 p3 = *reinterpret_cast<const f4*>(zb + 36);
        float v0[8] = {p0.x,p0.y,p0.z,p0.w,p1.x,p1.y,p1.z,p1.w};
        float v1[8] = {p2.x,p2.y,p2.z,p2.w,p3.x,p3.y,p3.z,p3.w};
        #pragma unroll
        for (int e = 0; e < 8; ++e) {
            _Float16 a = (_Float16)v0[e];
            zh0[h][e] = a; zl0[h][e] = (_Float16)(v0[e] - (float)a);
            _Float16 b = (_Float16)v1[e];
            zh1[h][e] = b; zl1[h][e] = (_Float16)(v1[e] - (float)b);
        }
    }

    float m1[2] = {-1e30f, -1e30f}, m2[2] = {-1e30f, -1e30f};
    int   bk[2] = {0, 0};

    // 16 independent code-tiles: 4 coalesced frag loads + c2 + 12 MFMA (R12-validated)
    #pragma unroll 4
    for (int tile = 0; tile < 16; ++tile) {
        half8 ah0 = fb[(tile * 4 + 0) * 64 + lane];
        half8 al0 = fb[(tile * 4 + 1) * 64 + lane];
        half8 ah1 = fb[(tile * 4 + 2) * 64 + lane];
        half8 al1 = fb[(tile * 4 + 3) * 64 + lane];
        f4 cv = c2t[tile * 4 + lh];
        f32x4 ci; ci[0] = -0.5f*cv.x; ci[1] = -0.5f*cv.y; ci[2] = -0.5f*cv.z; ci[3] = -0.5f*cv.w;
        #pragma unroll
        for (int h = 0; h < 2; ++h) {
            f32x4 acc = ci;
            acc = __builtin_amdgcn_mfma_f32_16x16x32_f16(ah0, h ? zh0[1] : zh0[0], acc, 0, 0, 0);
            acc = __builtin_amdgcn_mfma_f32_16x16x32_f16(ah1, h ? zh1[1] : zh1[0], acc, 0, 0, 0);
            acc = __builtin_amdgcn_mfma_f32_16x16x32_f16(ah0, h ? zl0[1] : zl0[0], acc, 0, 0, 0);
            acc = __builtin_amdgcn_mfma_f32_16x16x32_f16(ah1, h ? zl1[1] : zl1[0], acc, 0, 0, 0);
            acc = __builtin_amdgcn_mfma_f32_16x16x32_f16(al0, h ? zh0[1] : zh0[0], acc, 0, 0, 0);
            acc = __builtin_amdgcn_mfma_f32_16x16x32_f16(al1, h ? zh1[1] : zh1[0], acc, 0, 0, 0);
            #pragma unroll
            for (int r = 0; r < 4; ++r) {
                float v = acc[r];
                int code = tile * 16 + lh * 4 + r;
                m2[h] = __builtin_amdgcn_fmed3f(v, m1[h], m2[h]);  // == max(m2,min(v,m1))
                bool gt = v > m1[h];
                m1[h] = gt ? v : m1[h];
                bk[h] = gt ? code : bk[h];
            }
        }
    }

    // merge 4 lane-groups, rescue (rare, exact R4 arithmetic), write indices
    #pragma unroll
    for (int h = 0; h < 2; ++h) {
        #pragma unroll
        for (int off = 16; off <= 32; off <<= 1) {
            float om1 = __shfl_xor(m1[h], off, 64);
            float om2 = __shfl_xor(m2[h], off, 64);
            int   obk = __shfl_xor(bk[h], off, 64);
            m2[h] = fmaxf(fmaxf(m2[h], om2), fminf(m1[h], om1));
            bool better = (om1 > m1[h]) || (om1 == m1[h] && obk < bk[h]);
            m1[h] = better ? om1 : m1[h];
            bk[h] = better ? obk : bk[h];
        }
        bool need = (m1[h] - m2[h] < EPS2);
        unsigned mask = (unsigned)(__ballot(need)) & 0xFFFFu;
        while (mask) {
            int row = __builtin_ctz(mask); mask &= mask - 1;
            size_t rg = (size_t)(rowbase + h * 16 + row);
            const f4* zr4 = reinterpret_cast<const f4*>(z + (rg * 64 + m) * 64);
            float bs = -1e30f; int bkx = 0;
            #pragma unroll 1
            for (int j = 0; j < 4; ++j) {
                int k = j * 64 + lane;
                float s = -0.5f * c2ws[m * 256 + k];
                #pragma unroll
                for (int d4 = 0; d4 < 16; ++d4) {
                    f4 c = cb4m[k * 16 + d4];
                    f4 zz = zr4[d4];
                    s = fmaf(zz.x, c.x, s); s = fmaf(zz.y, c.y, s);
                    s = fmaf(zz.z, c.z, s); s = fmaf(zz.w, c.w, s);
                }
                if (s > bs) { bs = s; bkx = k; }
            }
            #pragma unroll
            for (int off = 1; off < 64; off <<= 1) {
                float ov = __shfl_xor(bs, off, 64);
                int   ok = __shfl_xor(bkx, off, 64);
                if (ov > bs || (ov == bs && ok < bkx)) { bs = ov; bkx = ok; }
            }
            bk[h] = (l15 == row) ? bkx : bk[h];
        }
        if (lane < 16)
            idxws[m * 4096 + rowbase + h * 16 + lane] = bk[h];
    }
}

// ---- epilogue: pure bandwidth. Block = 2 full z-rows (128 (b,m)-rows); all
//      z/out/idx accesses contiguous; cb gather L2-resident; exact fp32 loss. ----
__global__ __launch_bounds__(256) void pq_epi(
    const float* __restrict__ z, const float* __restrict__ cb,
    const int* __restrict__ idxws,
    float* __restrict__ out, float* __restrict__ partial)
{
    __shared__ float sW[4];
    const int tid = threadIdx.x, bx = blockIdx.x;
    const int b0 = bx * 2;
    const int r = tid >> 1, h = tid & 1;
    const int b = b0 + (r >> 6), m = r & 63;
    const int w = tid >> 6, lane = tid & 63;

    int k = idxws[m * 4096 + b];
    const f4* q4 = reinterpret_cast<const f4*>(cb + ((size_t)(m * 256 + k)) * 64) + h * 8;
    const f4* z4 = reinterpret_cast<const f4*>(z + ((size_t)b * 64 + m) * 64) + h * 8;
    f4*       o4 = reinterpret_cast<f4*>(out + ((size_t)b * 64 + m) * 64) + h * 8;

    float l0 = 0.f, l1 = 0.f;
    #pragma unroll
    for (int c = 0; c < 8; ++c) {
        f4 qv = q4[c], zv = z4[c];      // exact codebook copy, exact fp32 z
        o4[c] = qv;
        float d0 = qv.x - zv.x, d1 = qv.y - zv.y, d2 = qv.z - zv.z, d3 = qv.w - zv.w;
        l0 = fmaf(d0, d0, l0); l1 = fmaf(d1, d1, l1);
        l0 = fmaf(d2, d2, l0); l1 = fmaf(d3, d3, l1);
    }
    float lsum = l0 + l1;

    if (tid < 128) {                     // fp32 index output, fully contiguous
        int b2 = b0 + (tid >> 6), m2 = tid & 63;
        out[IDX_BASE + (size_t)b2 * 64 + m2] = (float)idxws[m2 * 4096 + b2];
    }

    #pragma unroll
    for (int off = 1; off < 64; off <<= 1) lsum += __shfl_xor(lsum, off, 64);
    if (lane == 0) sW[w] = lsum;
    __syncthreads();
    if (tid == 0) partial[bx] = (sW[0] + sW[1]) + (sW[2] + sW[3]);
}

// ---- deterministic final reduction of 2048 block partials -> q_loss ----
__global__ __launch_bounds__(256) void pq_loss(const float* __restrict__ partial,
                                               float* __restrict__ out)
{
    __shared__ float sW[4];
    float s = 0.f;
    #pragma unroll
    for (int i = 0; i < 8; ++i) s += partial[threadIdx.x + i * 256];
    #pragma unroll
    for (int off = 1; off < 64; off <<= 1) s += __shfl_xor(s, off, 64);
    if ((threadIdx.x & 63) == 0) sW[threadIdx.x >> 6] = s;
    __syncthreads();
    if (threadIdx.x == 0)
        out[LOSS_IDX] = ((sW[0] + sW[1]) + (sW[2] + sW[3])) * (1.25f / 16777216.0f);
}

extern "C" void kernel_launch(void* const* d_in, const int* in_sizes, int n_in,
                              void* d_out, int out_size, void* d_ws, size_t ws_size,
                              hipStream_t stream) {
    const float* zp  = (const float*)d_in[0];
    const float* cbp = (const float*)d_in[1];
    float* outp = (float*)d_out;
    float* c2ws = (float*)d_ws;                          // 16384 floats (64 KB)
    half8* frag = (half8*)((float*)d_ws + 16384);        // 4 MB
    int*   idxw = (int*)((float*)d_ws + 16384 + 1048576);// 1 MB (256K ints)
    float* part = (float*)d_ws + 16384 + 1048576 + 262144; // 2048 floats

    pq_frag <<<dim3(64),   dim3(256), 0, stream>>>(cbp, frag, c2ws);
    pq_score<<<dim3(2048), dim3(256), 0, stream>>>(zp, cbp, c2ws, frag, idxw);
    pq_epi  <<<dim3(2048), dim3(256), 0, stream>>>(zp, cbp, idxw, outp, part);
    pq_loss <<<dim3(1),    dim3(256), 0, stream>>>(part, outp);
}

// Round 14
// 97.320 us; speedup vs baseline: 1.1226x; 1.1226x over previous
//
#include <hip/hip_runtime.h>

#define IDX_BASE 16777216UL   // 4096*64*64
#define LOSS_IDX 17039360UL   // IDX_BASE + 4096*64
#define EPS2 0.02f            // rescue window; covers f16x3 err (~1e-3) + key-mask err (~9e-4)

typedef float4 f4;
typedef _Float16 half8 __attribute__((ext_vector_type(8)));
typedef float f32x4 __attribute__((ext_vector_type(4)));

static __device__ __forceinline__ unsigned umax(unsigned a, unsigned b) { return a > b ? a : b; }
static __device__ __forceinline__ unsigned umin(unsigned a, unsigned b) { return a < b ? a : b; }
// monotone float->u32 (validated transform): order-preserving for all finite floats
static __device__ __forceinline__ unsigned f2mono(float s) {
    unsigned u = __float_as_uint(s);
    return u ^ (unsigned)(((int)u >> 31) | 0x80000000);
}
static __device__ __forceinline__ float mono2f(unsigned v) {
    return __uint_as_float(v ^ (((unsigned)((int)(~v) >> 31)) | 0x80000000u));
}

// ---- precompute code A-fragments (f16 hi/lo) + fused c2 (R12-validated math),
//      parallelized 4x: grid 256, block = 64 codes of one m ----
__global__ __launch_bounds__(256) void pq_frag(const float* __restrict__ cb,
                                               half8* __restrict__ fragbuf,
                                               float* __restrict__ c2) {
    int bx = blockIdx.x, tid = threadIdx.x;
    int m = bx >> 2, sub = bx & 3;
    int w = tid >> 6, lane = tid & 63, lh = lane >> 4, l15 = lane & 15;
    const float* cbm = cb + (size_t)m * (256 * 64);
    half8* fbm = fragbuf + (size_t)m * (16 * 4 * 64);
    int tile = w * 4 + sub;
    int code = tile * 16 + l15;
    const float* crow = cbm + code * 64 + lh * 8;
    float ss = 0.f;
    #pragma unroll
    for (int s = 0; s < 2; ++s) {
        f4 a = *reinterpret_cast<const f4*>(crow + s * 32);
        f4 b = *reinterpret_cast<const f4*>(crow + s * 32 + 4);
        float v[8] = {a.x, a.y, a.z, a.w, b.x, b.y, b.z, b.w};
        half8 hi, lo;
        #pragma unroll
        for (int e = 0; e < 8; ++e) {
            _Float16 h = (_Float16)v[e];
            hi[e] = h; lo[e] = (_Float16)(v[e] - (float)h);
            ss = fmaf(v[e], v[e], ss);
        }
        fbm[(tile * 4 + s * 2 + 0) * 64 + lane] = hi;
        fbm[(tile * 4 + s * 2 + 1) * 64 + lane] = lo;
    }
    ss += __shfl_xor(ss, 16, 64);
    ss += __shfl_xor(ss, 32, 64);
    if (lh == 0) c2[m * 256 + code] = ss;
}

// ---- fused main: wave = 64 rows x 256 codes (packed-key tree top-2),
//      LDS only for the sBest handoff; epilogue fused with clean stores. ----
__global__ __launch_bounds__(256, 3) void pq_main(
    const float* __restrict__ z, const float* __restrict__ cb,
    const float* __restrict__ c2ws, const half8* __restrict__ fragbuf,
    float* __restrict__ out, float* __restrict__ partial)
{
    __shared__ int   sBest[256];
    __shared__ float sW[4];

    const int tid = threadIdx.x, bx = blockIdx.x;
    const int m = ((bx & 7) << 3) | ((bx >> 3) & 7);   // XCD-aware m-octet (R11-proven)
    const int chunk = bx >> 6;                          // 0..15 (256 rows each)
    const int w = tid >> 6, lane = tid & 63;
    const int lh = lane >> 4, l15 = lane & 15;
    const int rowbase = chunk * 256 + w * 64;
    const unsigned payBase = 255u - (unsigned)(lh * 4);

    const float* __restrict__ cbm = cb + (size_t)m * (256 * 64);
    const f4* cb4m = reinterpret_cast<const f4*>(cbm);
    const half8* __restrict__ fb = fragbuf + (size_t)m * (16 * 4 * 64);
    const f4* __restrict__ c2t = reinterpret_cast<const f4*>(c2ws + m * 256);

    // ---- resident z B-fragments for 4 row-tiles (R10-validated conversion) ----
    half8 zh[4][2], zl[4][2];
    #pragma unroll
    for (int h = 0; h < 4; ++h) {
        size_t rh = (size_t)(rowbase + h * 16 + l15);
        const float* zb = z + (rh * 64 + m) * 64 + lh * 8;
        f4 p0 = *reinterpret_cast<const f4*>(zb);
        f4 p1 = *reinterpret_cast<const f4*>(zb + 4);
        f4 p2 = *reinterpret_cast<const f4*>(zb + 32);
        f4 p3 = *reinterpret_cast<const f4*>(zb + 36);
        float v0[8] = {p0.x,p0.y,p0.z,p0.w,p1.x,p1.y,p1.z,p1.w};
        float v1[8] = {p2.x,p2.y,p2.z,p2.w,p3.x,p3.y,p3.z,p3.w};
        #pragma unroll
        for (int e = 0; e < 8; ++e) {
            _Float16 a = (_Float16)v0[e];
            zh[h][0][e] = a; zl[h][0][e] = (_Float16)(v0[e] - (float)a);
            _Float16 b = (_Float16)v1[e];
            zh[h][1][e] = b; zl[h][1][e] = (_Float16)(v1[e] - (float)b);
        }
    }

    unsigned K1[4] = {0, 0, 0, 0}, K2[4] = {0, 0, 0, 0};

    // ---- 16 code-tiles: 4 frag loads + c2 + 24 MFMA + tree top-2 ----
    #pragma unroll 2
    for (int tile = 0; tile < 16; ++tile) {
        half8 ah0 = fb[(tile * 4 + 0) * 64 + lane];
        half8 al0 = fb[(tile * 4 + 1) * 64 + lane];
        half8 ah1 = fb[(tile * 4 + 2) * 64 + lane];
        half8 al1 = fb[(tile * 4 + 3) * 64 + lane];
        f4 cv = c2t[tile * 4 + lh];
        f32x4 ci; ci[0] = -0.5f*cv.x; ci[1] = -0.5f*cv.y; ci[2] = -0.5f*cv.z; ci[3] = -0.5f*cv.w;
        #pragma unroll
        for (int h = 0; h < 4; ++h) {
            f32x4 acc = ci;
            acc = __builtin_amdgcn_mfma_f32_16x16x32_f16(ah0, zh[h][0], acc, 0, 0, 0);
            acc = __builtin_amdgcn_mfma_f32_16x16x32_f16(ah1, zh[h][1], acc, 0, 0, 0);
            acc = __builtin_amdgcn_mfma_f32_16x16x32_f16(ah0, zl[h][0], acc, 0, 0, 0);
            acc = __builtin_amdgcn_mfma_f32_16x16x32_f16(ah1, zl[h][1], acc, 0, 0, 0);
            acc = __builtin_amdgcn_mfma_f32_16x16x32_f16(al0, zh[h][0], acc, 0, 0, 0);
            acc = __builtin_amdgcn_mfma_f32_16x16x32_f16(al1, zh[h][1], acc, 0, 0, 0);
            unsigned kk0 = (f2mono(acc[0]) & 0xFFFFFF00u) | (payBase - (unsigned)(tile * 16 + 0));
            unsigned kk1 = (f2mono(acc[1]) & 0xFFFFFF00u) | (payBase - (unsigned)(tile * 16 + 1));
            unsigned kk2 = (f2mono(acc[2]) & 0xFFFFFF00u) | (payBase - (unsigned)(tile * 16 + 2));
            unsigned kk3 = (f2mono(acc[3]) & 0xFFFFFF00u) | (payBase - (unsigned)(tile * 16 + 3));
            unsigned a  = umax(kk0, kk1), b2 = umin(kk0, kk1);
            unsigned c  = umax(kk2, kk3), d  = umin(kk2, kk3);
            unsigned t1 = umax(a, c);
            unsigned t2 = umax(umin(a, c), umax(b2, d));
            K2[h] = umax(umax(K2[h], t2), umin(K1[h], t1));
            K1[h] = umax(K1[h], t1);
        }
    }

    // ---- per row-tile: lane-group merge (payload = tie-break), rescue, handoff ----
    #pragma unroll
    for (int h = 0; h < 4; ++h) {
        #pragma unroll
        for (int off = 16; off <= 32; off <<= 1) {
            unsigned o1 = (unsigned)__shfl_xor((int)K1[h], off, 64);
            unsigned o2 = (unsigned)__shfl_xor((int)K2[h], off, 64);
            K2[h] = umax(umax(K2[h], o2), umin(K1[h], o1));
            K1[h] = umax(K1[h], o1);
        }
        int cd = 255 - (int)(K1[h] & 0xFFu);
        float s1 = mono2f(K1[h] & 0xFFFFFF00u);
        float s2 = mono2f(K2[h] & 0xFFFFFF00u);
        bool need = (s1 - s2) < EPS2;
        unsigned mask = (unsigned)(__ballot(need)) & 0xFFFFu;
        while (mask) {                       // rescue: exact fp32 (validated R4 math)
            int row = __builtin_ctz(mask); mask &= mask - 1;
            size_t rg = (size_t)(rowbase + h * 16 + row);
            const f4* zr4 = reinterpret_cast<const f4*>(z + (rg * 64 + m) * 64);
            float bs = -1e30f; int bkx = 0;
            #pragma unroll 1
            for (int j = 0; j < 4; ++j) {
                int k = j * 64 + lane;
                float s = -0.5f * c2ws[m * 256 + k];
                #pragma unroll
                for (int d4 = 0; d4 < 16; ++d4) {
                    f4 cc = cb4m[k * 16 + d4];
                    f4 zz = zr4[d4];
                    s = fmaf(zz.x, cc.x, s); s = fmaf(zz.y, cc.y, s);
                    s = fmaf(zz.z, cc.z, s); s = fmaf(zz.w, cc.w, s);
                }
                if (s > bs) { bs = s; bkx = k; }
            }
            #pragma unroll
            for (int off = 1; off < 64; off <<= 1) {
                float ov = __shfl_xor(bs, off, 64);
                int   ok = __shfl_xor(bkx, off, 64);
                if (ov > bs || (ov == bs && ok < bkx)) { bs = ov; bkx = ok; }
            }
            if (l15 == row) cd = bkx;
        }
        if (lane < 16) sBest[w * 64 + h * 16 + lane] = cd;
    }
    __syncthreads();

    // ---- fused epilogue: R7/R13-proven pattern (128 B contiguous per lane) ----
    float lsum = 0.f;
    #pragma unroll
    for (int it = 0; it < 2; ++it) {
        int row = it * 128 + (tid >> 1);
        int hf  = tid & 1;
        int k   = sBest[row];
        size_t b = (size_t)(chunk * 256 + row);
        const f4* q4 = cb4m + (size_t)k * 16 + hf * 8;
        const f4* z4 = reinterpret_cast<const f4*>(z + (b * 64 + m) * 64) + hf * 8;
        f4*       o4 = reinterpret_cast<f4*>(out + (b * 64 + m) * 64) + hf * 8;
        float l0 = 0.f, l1 = 0.f;
        #pragma unroll
        for (int c = 0; c < 8; ++c) {
            f4 qv = q4[c], zv = z4[c];       // exact codebook copy, exact fp32 z
            o4[c] = qv;
            float d0 = qv.x - zv.x, d1 = qv.y - zv.y, d2 = qv.z - zv.z, d3 = qv.w - zv.w;
            l0 = fmaf(d0, d0, l0); l1 = fmaf(d1, d1, l1);
            l0 = fmaf(d2, d2, l0); l1 = fmaf(d3, d3, l1);
        }
        lsum += l0 + l1;
    }
    out[IDX_BASE + (size_t)(chunk * 256 + tid) * 64 + m] = (float)sBest[tid];

    #pragma unroll
    for (int off = 1; off < 64; off <<= 1) lsum += __shfl_xor(lsum, off, 64);
    if (lane == 0) sW[w] = lsum;
    __syncthreads();
    if (tid == 0) partial[bx] = (sW[0] + sW[1]) + (sW[2] + sW[3]);
}

// ---- deterministic final reduction of 1024 block partials -> q_loss ----
__global__ __launch_bounds__(256) void pq_loss(const float* __restrict__ partial,
                                               float* __restrict__ out)
{
    __shared__ float sW[4];
    float s = (partial[threadIdx.x]       + partial[threadIdx.x + 256])
            + (partial[threadIdx.x + 512] + partial[threadIdx.x + 768]);
    #pragma unroll
    for (int off = 1; off < 64; off <<= 1) s += __shfl_xor(s, off, 64);
    if ((threadIdx.x & 63) == 0) sW[threadIdx.x >> 6] = s;
    __syncthreads();
    if (threadIdx.x == 0)
        out[LOSS_IDX] = ((sW[0] + sW[1]) + (sW[2] + sW[3])) * (1.25f / 16777216.0f);
}

extern "C" void kernel_launch(void* const* d_in, const int* in_sizes, int n_in,
                              void* d_out, int out_size, void* d_ws, size_t ws_size,
                              hipStream_t stream) {
    const float* zp  = (const float*)d_in[0];
    const float* cbp = (const float*)d_in[1];
    float* outp = (float*)d_out;
    float* c2ws = (float*)d_ws;                          // 16384 floats (64 KB)
    half8* frag = (half8*)((float*)d_ws + 16384);        // 4 MB
    float* part = (float*)d_ws + 16384 + 1048576;        // 1024 floats

    pq_frag<<<dim3(256),  dim3(256), 0, stream>>>(cbp, frag, c2ws);
    pq_main<<<dim3(1024), dim3(256), 0, stream>>>(zp, cbp, c2ws, frag, outp, part);
    pq_loss<<<dim3(1),    dim3(256), 0, stream>>>(part, outp);
}

// Round 15
// 84.584 us; speedup vs baseline: 1.2917x; 1.1506x over previous
//
#include <hip/hip_runtime.h>

#define IDX_BASE 16777216UL   // 4096*64*64
#define LOSS_IDX 17039360UL   // IDX_BASE + 4096*64
#define EPS2 0.02f            // rescue window; covers f16x3 err (~1e-3) + key-mask err (R14-validated)

typedef float4 f4;
typedef _Float16 half8 __attribute__((ext_vector_type(8)));
typedef float f32x4 __attribute__((ext_vector_type(4)));

static __device__ __forceinline__ unsigned umax(unsigned a, unsigned b) { return a > b ? a : b; }
static __device__ __forceinline__ unsigned umin(unsigned a, unsigned b) { return a < b ? a : b; }
// monotone float<->u32 (R14-validated)
static __device__ __forceinline__ unsigned f2mono(float s) {
    unsigned u = __float_as_uint(s);
    return u ^ (unsigned)(((int)u >> 31) | 0x80000000);
}
static __device__ __forceinline__ float mono2f(unsigned v) {
    return __uint_as_float(v ^ (((unsigned)((int)(~v) >> 31)) | 0x80000000u));
}

__device__ __forceinline__ void gload_lds16(const float* g, float* s) {
    __builtin_amdgcn_global_load_lds(
        (const __attribute__((address_space(1))) unsigned int*)g,
        (__attribute__((address_space(3))) unsigned int*)s, 16, 0, 0);
}

// ---- precompute code A-fragments (f16 hi/lo) + fused c2 (R14-validated, 4x parallel) ----
__global__ __launch_bounds__(256) void pq_frag(const float* __restrict__ cb,
                                               half8* __restrict__ fragbuf,
                                               float* __restrict__ c2) {
    int bx = blockIdx.x, tid = threadIdx.x;
    int m = bx >> 2, sub = bx & 3;
    int w = tid >> 6, lane = tid & 63, lh = lane >> 4, l15 = lane & 15;
    const float* cbm = cb + (size_t)m * (256 * 64);
    half8* fbm = fragbuf + (size_t)m * (16 * 4 * 64);
    int tile = w * 4 + sub;
    int code = tile * 16 + l15;
    const float* crow = cbm + code * 64 + lh * 8;
    float ss = 0.f;
    #pragma unroll
    for (int s = 0; s < 2; ++s) {
        f4 a = *reinterpret_cast<const f4*>(crow + s * 32);
        f4 b = *reinterpret_cast<const f4*>(crow + s * 32 + 4);
        float v[8] = {a.x, a.y, a.z, a.w, b.x, b.y, b.z, b.w};
        half8 hi, lo;
        #pragma unroll
        for (int e = 0; e < 8; ++e) {
            _Float16 h = (_Float16)v[e];
            hi[e] = h; lo[e] = (_Float16)(v[e] - (float)h);
            ss = fmaf(v[e], v[e], ss);
        }
        fbm[(tile * 4 + s * 2 + 0) * 64 + lane] = hi;
        fbm[(tile * 4 + s * 2 + 1) * 64 + lane] = lo;
    }
    ss += __shfl_xor(ss, 16, 64);
    ss += __shfl_xor(ss, 32, 64);
    if (lh == 0) c2[m * 256 + code] = ss;
}

// Block = one m x 128 rows, 4 waves; wave w owns codes w*64..+63 (A-frags resident).
// z staged fp32 in LDS (swizzled). R11 structure + packed-key top-2 (R14 math).
__global__ __launch_bounds__(256, 3) void pq_main(
    const float* __restrict__ z, const float* __restrict__ cb,
    const float* __restrict__ c2ws, const half8* __restrict__ fragbuf,
    float* __restrict__ out, float* __restrict__ partial)
{
    __shared__ f4       sZ4[128 * 16];   // 32 KB; sZ4[r*16+c4] = z[r][(c4^(r&7))*4..]
    __shared__ unsigned sK1[4 * 128];
    __shared__ unsigned sK2[4 * 128];
    __shared__ int      sBest[128];
    __shared__ float    sW[4];

    const int tid = threadIdx.x, bx = blockIdx.x;
    const int m = ((bx & 7) << 3) | ((bx >> 3) & 7);   // XCD-aware m-octet (R11-proven)
    const int chunk = bx >> 6;                          // 0..31
    const int w = tid >> 6, lane = tid & 63;
    const int lh = lane >> 4, l15 = lane & 15;
    const unsigned payBase = 255u - (unsigned)(w * 64 + lh * 4);  // payload = 255 - global code

    const float* __restrict__ cbm = cb + (size_t)m * (256 * 64);
    const f4* cb4m = reinterpret_cast<const f4*>(cbm);

    // ---- stage z fp32 (pre-swizzled source -> linear LDS), fire DMA first [R11] ----
    #pragma unroll
    for (int i = 0; i < 8; ++i) {
        int unit = i * 256 + w * 64 + lane;
        int row = unit >> 4, c4 = unit & 15;
        int c4p = c4 ^ (row & 7);
        const float* src = z + ((size_t)(chunk * 128 + row) * 64 + m) * 64 + c4p * 4;
        gload_lds16(src, (float*)&sZ4[i * 256 + w * 64]);
    }

    // ---- A-fragments: 16 coalesced loads from fragbuf [R11] ----
    const half8* __restrict__ fb = fragbuf + (size_t)m * (16 * 4 * 64);
    half8 ah[4][2], al[4][2];
    #pragma unroll
    for (int t = 0; t < 4; ++t) {
        #pragma unroll
        for (int s = 0; s < 2; ++s) {
            ah[t][s] = fb[((w * 4 + t) * 4 + s * 2 + 0) * 64 + lane];
            al[t][s] = fb[((w * 4 + t) * 4 + s * 2 + 1) * 64 + lane];
        }
    }
    // ---- c2 init per lane: k = w*64 + t*16 + lh*4 + r [R11] ----
    const f4* __restrict__ c2t = reinterpret_cast<const f4*>(c2ws + m * 256);
    f32x4 c2i[4];
    #pragma unroll
    for (int t = 0; t < 4; ++t) {
        f4 cv = c2t[(w * 4 + t) * 4 + lh];
        c2i[t][0] = -0.5f*cv.x; c2i[t][1] = -0.5f*cv.y;
        c2i[t][2] = -0.5f*cv.z; c2i[t][3] = -0.5f*cv.w;
    }

    __syncthreads();   // z staged

    // ---- main: 4 row-tile PAIRS x {convert x2 + 4x(2x6) MFMA + packed top-2} ----
    #pragma unroll 1
    for (int rtp = 0; rtp < 4; ++rtp) {
        half8 bh0[2], bl0[2], bh1[2], bl1[2];
        #pragma unroll
        for (int h = 0; h < 2; ++h) {
            const int row = (rtp * 2 + h) * 16 + l15;
            const int swz = row & 7;
            const f4* zr = &sZ4[row * 16];
            const int c0 = lh << 1;
            f4 a0 = zr[(c0)     ^ swz];
            f4 a1 = zr[(c0 + 1) ^ swz];
            f4 a2 = zr[(c0 + 8) ^ swz];
            f4 a3 = zr[(c0 + 9) ^ swz];
            float v0[8] = {a0.x,a0.y,a0.z,a0.w,a1.x,a1.y,a1.z,a1.w};
            float v1[8] = {a2.x,a2.y,a2.z,a2.w,a3.x,a3.y,a3.z,a3.w};
            #pragma unroll
            for (int e = 0; e < 8; ++e) {
                _Float16 h0 = (_Float16)v0[e];
                bh0[h][e] = h0; bl0[h][e] = (_Float16)(v0[e] - (float)h0);
                _Float16 h1 = (_Float16)v1[e];
                bh1[h][e] = h1; bl1[h][e] = (_Float16)(v1[e] - (float)h1);
            }
        }
        unsigned K1[2] = {0u, 0u}, K2[2] = {0u, 0u};
        #pragma unroll
        for (int t = 0; t < 4; ++t) {
            const unsigned pb = payBase - (unsigned)(t * 16);
            #pragma unroll
            for (int h = 0; h < 2; ++h) {
                f32x4 acc = c2i[t];
                acc = __builtin_amdgcn_mfma_f32_16x16x32_f16(ah[t][0], bh0[h], acc, 0, 0, 0);
                acc = __builtin_amdgcn_mfma_f32_16x16x32_f16(ah[t][1], bh1[h], acc, 0, 0, 0);
                acc = __builtin_amdgcn_mfma_f32_16x16x32_f16(ah[t][0], bl0[h], acc, 0, 0, 0);
                acc = __builtin_amdgcn_mfma_f32_16x16x32_f16(ah[t][1], bl1[h], acc, 0, 0, 0);
                acc = __builtin_amdgcn_mfma_f32_16x16x32_f16(al[t][0], bh0[h], acc, 0, 0, 0);
                acc = __builtin_amdgcn_mfma_f32_16x16x32_f16(al[t][1], bh1[h], acc, 0, 0, 0);
                unsigned kk0 = (f2mono(acc[0]) & 0xFFFFFF00u) | (pb - 0u);
                unsigned kk1 = (f2mono(acc[1]) & 0xFFFFFF00u) | (pb - 1u);
                unsigned kk2 = (f2mono(acc[2]) & 0xFFFFFF00u) | (pb - 2u);
                unsigned kk3 = (f2mono(acc[3]) & 0xFFFFFF00u) | (pb - 3u);
                unsigned a  = umax(kk0, kk1), b2 = umin(kk0, kk1);
                unsigned c  = umax(kk2, kk3), d  = umin(kk2, kk3);
                unsigned t1 = umax(a, c);
                unsigned t2 = umax(umin(a, c), umax(b2, d));
                K2[h] = umax(umax(K2[h], t2), umin(K1[h], t1));
                K1[h] = umax(K1[h], t1);
            }
        }
        #pragma unroll
        for (int h = 0; h < 2; ++h) {
            #pragma unroll
            for (int off = 16; off <= 32; off <<= 1) {   // merge 4 lane-groups per row
                unsigned o1 = (unsigned)__shfl_xor((int)K1[h], off, 64);
                unsigned o2 = (unsigned)__shfl_xor((int)K2[h], off, 64);
                K2[h] = umax(umax(K2[h], o2), umin(K1[h], o1));
                K1[h] = umax(K1[h], o1);
            }
            if (lane < 16) {
                int r2 = (rtp * 2 + h) * 16 + lane;
                sK1[w * 128 + r2] = K1[h];
                sK2[w * 128 + r2] = K2[h];
            }
        }
    }
    __syncthreads();

    // ---- per-row merge across 4 waves (packed umax tree); flag near-ties ----
    if (tid < 128) {
        unsigned G1 = 0u, G2 = 0u;
        #pragma unroll
        for (int w2 = 0; w2 < 4; ++w2) {
            unsigned k1w = sK1[w2 * 128 + tid];
            unsigned k2w = sK2[w2 * 128 + tid];
            G2 = umax(umax(G2, k2w), umin(G1, k1w));
            G1 = umax(G1, k1w);
        }
        float s1 = mono2f(G1 & 0xFFFFFF00u);
        float s2 = mono2f(G2 & 0xFFFFFF00u);
        sBest[tid] = (s1 - s2 < EPS2) ? -1 : (int)(255u - (G1 & 0xFFu));
    }
    __syncthreads();

    // ---- rescue (rare): exact fp32 rescan (validated R4 arithmetic) [R11] ----
    for (int row = w; row < 128; row += 4) {
        if (sBest[row] >= 0) continue;            // wave-uniform
        int swz = row & 7;
        float bs = -1e30f; int bk = 0;
        #pragma unroll 1
        for (int j = 0; j < 4; ++j) {
            int k = j * 64 + lane;
            float s = -0.5f * c2ws[m * 256 + k];
            #pragma unroll
            for (int d4 = 0; d4 < 16; ++d4) {
                f4 cvv = cb4m[k * 16 + d4];
                f4 zz  = sZ4[row * 16 + (d4 ^ swz)];
                s = fmaf(zz.x, cvv.x, s); s = fmaf(zz.y, cvv.y, s);
                s = fmaf(zz.z, cvv.z, s); s = fmaf(zz.w, cvv.w, s);
            }
            if (s > bs) { bs = s; bk = k; }
        }
        #pragma unroll
        for (int off = 1; off < 64; off <<= 1) {
            float ov = __shfl_xor(bs, off, 64);
            int   ok = __shfl_xor(bk, off, 64);
            if (ov > bs || (ov == bs && ok < bk)) { bs = ov; bk = ok; }
        }
        if (lane == 0) sBest[row] = bk;
    }
    __syncthreads();

    // ---- outputs (R7/R11-validated: per-lane contiguous 128 B, z from LDS) ----
    float lsum = 0.f;
    {
        int row = tid >> 1, h = tid & 1;
        int k = sBest[row];
        int b = chunk * 128 + row;
        int swz = row & 7;
        const f4* q4 = cb4m + (size_t)k * 16 + h * 8;
        f4*       o4 = reinterpret_cast<f4*>(out + ((size_t)b * 64 + m) * 64) + h * 8;
        float l0 = 0.f, l1 = 0.f;
        #pragma unroll
        for (int c = 0; c < 8; ++c) {
            f4 qv = q4[c];
            f4 zv = sZ4[row * 16 + (((h << 3) + c) ^ swz)];
            o4[c] = qv;
            float d0 = qv.x - zv.x, d1 = qv.y - zv.y, d2 = qv.z - zv.z, d3 = qv.w - zv.w;
            l0 = fmaf(d0, d0, l0); l1 = fmaf(d1, d1, l1);
            l0 = fmaf(d2, d2, l0); l1 = fmaf(d3, d3, l1);
        }
        lsum = l0 + l1;
    }
    if (tid < 128)
        out[IDX_BASE + (size_t)(chunk * 128 + tid) * 64 + m] = (float)sBest[tid];
    #pragma unroll
    for (int off = 1; off < 64; off <<= 1) lsum += __shfl_xor(lsum, off, 64);
    if (lane == 0) sW[w] = lsum;
    __syncthreads();
    if (tid == 0) partial[bx] = (sW[0] + sW[1]) + (sW[2] + sW[3]);
}

// ---- deterministic final reduction of 2048 block partials -> q_loss ----
__global__ __launch_bounds__(256) void pq_loss(const float* __restrict__ partial,
                                               float* __restrict__ out)
{
    __shared__ float sW[4];
    float s = 0.f;
    #pragma unroll
    for (int i = 0; i < 8; ++i) s += partial[threadIdx.x + i * 256];
    #pragma unroll
    for (int off = 1; off < 64; off <<= 1) s += __shfl_xor(s, off, 64);
    if ((threadIdx.x & 63) == 0) sW[threadIdx.x >> 6] = s;
    __syncthreads();
    if (threadIdx.x == 0)
        out[LOSS_IDX] = ((sW[0] + sW[1]) + (sW[2] + sW[3])) * (1.25f / 16777216.0f);
}

extern "C" void kernel_launch(void* const* d_in, const int* in_sizes, int n_in,
                              void* d_out, int out_size, void* d_ws, size_t ws_size,
                              hipStream_t stream) {
    const float* zp  = (const float*)d_in[0];
    const float* cbp = (const float*)d_in[1];
    float* outp = (float*)d_out;
    float* c2ws = (float*)d_ws;                        // 16384 floats (64 KB)
    half8* frag = (half8*)((float*)d_ws + 16384);      // 4 MB
    float* part = (float*)d_ws + 16384 + 1048576;      // 2048 floats

    pq_frag<<<dim3(256),  dim3(256), 0, stream>>>(cbp, frag, c2ws);
    pq_main<<<dim3(2048), dim3(256), 0, stream>>>(zp, cbp, c2ws, frag, outp, part);
    pq_loss<<<dim3(1),    dim3(256), 0, stream>>>(part, outp);
}